// Round 11
// baseline (97.524 us; speedup 1.0000x reference)
//
#include <hip/hip_runtime.h>
#include <hip/hip_bf16.h>

#define BB 16
#define SS 2048
#define DD 1024
#define HH 16
#define KK 31
#define HK 496

typedef float f32x16 __attribute__((ext_vector_type(16)));
typedef float f32x4 __attribute__((ext_vector_type(4)));
typedef __bf16 bf16x8 __attribute__((ext_vector_type(8)));

__device__ __forceinline__ unsigned f2bf(float x) {
  unsigned u = __float_as_uint(x);
  unsigned r = u + 0x7FFFu + ((u >> 16) & 1u);
  return r >> 16;
}

__device__ __forceinline__ void gll16(const void* g, void* l) {
  __builtin_amdgcn_global_load_lds(
      (const __attribute__((address_space(1))) unsigned int*)g,
      (__attribute__((address_space(3))) unsigned int*)l, 16, 0, 0);
}

// ---------------- prep: W_q (f32, D x 496) -> bf16 image, padded N=512 (R6/R9).
// Bimg[ks][slice][w][nt][lane][e] = W[k=ks*32+slice*16+(lane>>5)*8+e][col=w*64+nt*32+(lane&31)]
__global__ void prep_kernel(const float* __restrict__ Wq,
                            unsigned short* __restrict__ Bimg) {
  int idx = blockIdx.x * 256 + threadIdx.x;  // < 524288
  int e = idx & 7;
  int lane = (idx >> 3) & 63;
  int nt = (idx >> 9) & 1;
  int w = (idx >> 10) & 7;
  int slice = (idx >> 13) & 1;
  int ks = idx >> 14;
  int k = ks * 32 + slice * 16 + (lane >> 5) * 8 + e;
  int c = w * 64 + nt * 32 + (lane & 31);
  int h = c >> 5, j = c & 31;
  float v = (j < KK) ? Wq[k * HK + h * KK + j] : 0.f;
  Bimg[idx] = (unsigned short)f2bf(v);
}

// ---------------- ksum: (B,S,H), 16 rows per block
__global__ __launch_bounds__(256) void ksum_kernel(const float* __restrict__ key,
                                                   float* __restrict__ ksum) {
  const int tid = threadIdx.x;
  const int r0 = blockIdx.x * 16;
#pragma unroll 4
  for (int rr = 0; rr < 16; ++rr) {
    const int row = r0 + rr;
    const f32x4 v = *((const f32x4*)(key + (size_t)row * DD) + tid);
    float p = v.x + v.y + v.z + v.w;
    p += __shfl_xor(p, 1);
    p += __shfl_xor(p, 2);
    p += __shfl_xor(p, 4);
    p += __shfl_xor(p, 8);
    if ((tid & 15) == 0) ksum[(size_t)row * HH + (tid >> 4)] = p;
  }
}

// ---------------- fused GEMM (32x32x16 bf16) + conv + transpose
// BM=128, BN=512, BK=32, 256 blocks (1/CU), 8 waves.
// 3-deep LDS ring of 48KB slots (A 16KB f32 + B 32KB bf16), all via
// global_load_lds; stage always 2 steps ahead; vmcnt(12) counted waits.
// Halves total staged bytes vs BM=64 (B re-pull is 32GB/BM).
__global__ __launch_bounds__(512, 2) void mca_kernel(
    const float* __restrict__ q, const float* __restrict__ bq,
    const float* __restrict__ convb, const float* __restrict__ ksum,
    const unsigned short* __restrict__ Bimg, float* __restrict__ out) {
  extern __shared__ char smem[];
  const int tid = threadIdx.x;
  const int w = tid >> 6, lane = tid & 63;
  const int l31 = lane & 31, hi = lane >> 5;
  const int bid = blockIdx.x;
  const int bb = bid >> 4;
  const int t0 = (bid & 15) << 7;

  const float* qblk = q + ((size_t)(bb * SS + t0)) * DD;
  const char* const BimgB = (const char*)Bimg;

  // A staging: 1024 granules (128 rows x 8 slots); thread t handles linear
  // granules t and t+512. LDS dest is LINEAR (gidx*16); the source granule
  // is pre-swizzled: slot s holds source granule s^(row&7).  [R9-proven]
  const int g0r = tid >> 3, gs = tid & 7;
  const int g1r = g0r + 64;
  const float* aS0 = qblk + (size_t)g0r * DD + ((gs ^ (g0r & 7)) << 2);
  const float* aS1 = qblk + (size_t)g1r * DD + ((gs ^ (g1r & 7)) << 2);

  f32x16 acc[4][2];
#pragma unroll
  for (int mt = 0; mt < 4; ++mt)
#pragma unroll
    for (int nt = 0; nt < 2; ++nt)
#pragma unroll
      for (int r = 0; r < 16; ++r) acc[mt][nt][r] = 0.f;

  auto stage = [&](int ks, char* base) {
    gll16(aS0 + ks * 32, base + w * 1024);           // A rows 0..63
    gll16(aS1 + ks * 32, base + 8192 + w * 1024);    // A rows 64..127
    char* Bd = base + 16384;
#pragma unroll
    for (int r = 0; r < 4; ++r)                       // B 32KB linear copy
      gll16(BimgB + (size_t)ks * 32768 + r * 8192 + (size_t)tid * 16,
            Bd + r * 8192 + w * 1024);
  };

  // A fragment: row = mt*32+l31, k-octet u = s*2+hi; granules (2u,2u+1)
  // live at slot ^(row&7); f32 -> bf16 via v_cvt_pk_bf16_f32.  [R9-proven]
  auto afrag = [&](const char* Ad, int s, int mt) -> bf16x8 {
    const int row = mt * 32 + l31;
    const int u = s * 2 + hi;
    const int q0 = (2 * u) ^ (row & 7);
    const int q1 = (2 * u + 1) ^ (row & 7);
    const f32x4 lo = *(const f32x4*)(Ad + row * 128 + q0 * 16);
    const f32x4 hh = *(const f32x4*)(Ad + row * 128 + q1 * 16);
    unsigned p0, p1, p2, p3;
    asm("v_cvt_pk_bf16_f32 %0, %1, %2" : "=v"(p0) : "v"(lo.x), "v"(lo.y));
    asm("v_cvt_pk_bf16_f32 %0, %1, %2" : "=v"(p1) : "v"(lo.z), "v"(lo.w));
    asm("v_cvt_pk_bf16_f32 %0, %1, %2" : "=v"(p2) : "v"(hh.x), "v"(hh.y));
    asm("v_cvt_pk_bf16_f32 %0, %1, %2" : "=v"(p3) : "v"(hh.z), "v"(hh.w));
    union { unsigned u4[4]; bf16x8 b; } cv;
    cv.u4[0] = p0; cv.u4[1] = p1; cv.u4[2] = p2; cv.u4[3] = p3;
    return cv.b;
  };
  auto bfrag = [&](const char* Bd, int s, int nt) -> bf16x8 {
    return *(const bf16x8*)(Bd + s * 16384 + w * 2048 + nt * 1024 + lane * 16);
  };
  auto compute = [&](const char* base) {
    const char* Ad = base;
    const char* Bd = base + 16384;
#pragma unroll
    for (int s = 0; s < 2; ++s) {
      bf16x8 b0 = bfrag(Bd, s, 0);
      bf16x8 b1 = bfrag(Bd, s, 1);
#pragma unroll
      for (int mt = 0; mt < 4; ++mt) {
        bf16x8 a = afrag(Ad, s, mt);
        acc[mt][0] = __builtin_amdgcn_mfma_f32_32x32x16_bf16(a, b0, acc[mt][0], 0, 0, 0);
        acc[mt][1] = __builtin_amdgcn_mfma_f32_32x32x16_bf16(a, b1, acc[mt][1], 0, 0, 0);
      }
    }
  };

  // prologue: fill the 3-slot ring, wait for step 0 (12 younger outstanding)
  stage(0, smem);
  stage(1, smem + 49152);
  stage(2, smem + 98304);
  asm volatile("s_waitcnt vmcnt(12)" ::: "memory");
  __builtin_amdgcn_sched_barrier(0);
  __builtin_amdgcn_s_barrier();
  __builtin_amdgcn_sched_barrier(0);

#pragma unroll
  for (int ks = 0; ks < 32; ++ks) {
    char* base = smem + (ks % 3) * 49152;
    compute(base);
    __builtin_amdgcn_s_barrier();          // all waves done reading this slot
    __builtin_amdgcn_sched_barrier(0);
    if (ks + 3 < 32) stage(ks + 3, base);  // refill slot 2 steps ahead
    if (ks < 29) {
      asm volatile("s_waitcnt vmcnt(12)" ::: "memory");  // step ks+1 landed
    } else if (ks == 29) {
      asm volatile("s_waitcnt vmcnt(6)" ::: "memory");
    } else if (ks == 30) {
      asm volatile("s_waitcnt vmcnt(0)" ::: "memory");
    }
    __builtin_amdgcn_sched_barrier(0);
    __builtin_amdgcn_s_barrier();          // publish step ks+1
    __builtin_amdgcn_sched_barrier(0);
  }

  // ---- epilogue: conv over j (K=31) in f32; wave w -> heads w*2+nt ----
  float bqv[2], cb[2];
#pragma unroll
  for (int nt = 0; nt < 2; ++nt) {
    const int h = w * 2 + nt;
    bqv[nt] = (l31 < KK) ? bq[h * KK + l31] : 0.f;
    cb[nt] = convb[h];
  }

  __syncthreads();  // ring dead; reuse smem for ksum slice (160 rows x 16 heads)
  float* kl = reinterpret_cast<float*>(smem);
  for (int i = tid; i < 160 * 16; i += 512) {
    int trow = i >> 4, h = i & 15;
    int t = t0 + trow - 15;
    kl[trow * 17 + h] = (t >= 0 && t < SS) ? ksum[((size_t)bb * SS + t) * HH + h] : 0.f;
  }
  __syncthreads();

#pragma unroll
  for (int mt = 0; mt < 4; ++mt)
#pragma unroll
    for (int nt = 0; nt < 2; ++nt) {
      const int h = w * 2 + nt;
#pragma unroll
      for (int r = 0; r < 16; ++r) {
        const int tl = mt * 32 + (r & 3) + 8 * (r >> 2) + 4 * hi;
        float v = (acc[mt][nt][r] + bqv[nt]) * kl[(tl + l31) * 17 + h];
        v += __shfl_xor(v, 1);
        v += __shfl_xor(v, 2);
        v += __shfl_xor(v, 4);
        v += __shfl_xor(v, 8);
        v += __shfl_xor(v, 16);
        if (l31 == r)
          out[((size_t)(bb * HH + h)) * SS + t0 + tl] = v + cb[nt];
      }
    }
}

extern "C" void kernel_launch(void* const* d_in, const int* in_sizes, int n_in,
                              void* d_out, int out_size, void* d_ws, size_t ws_size,
                              hipStream_t stream) {
  const float* q   = (const float*)d_in[0];
  const float* key = (const float*)d_in[1];
  // d_in[2] (values) and d_in[3] (lengths) are unused by the reference
  const float* Wq  = (const float*)d_in[4];
  const float* bq  = (const float*)d_in[5];
  const float* cvb = (const float*)d_in[6];
  float* out = (float*)d_out;

  float* ksum = (float*)d_ws;                                        // 2 MB
  unsigned short* Bimg = (unsigned short*)((char*)d_ws + (2 << 20)); // 1 MB

  hipFuncSetAttribute((const void*)mca_kernel,
                      hipFuncAttributeMaxDynamicSharedMemorySize, 147456);

  prep_kernel<<<2048, 256, 0, stream>>>(Wq, Bimg);
  ksum_kernel<<<2048, 256, 0, stream>>>(key, ksum);
  mca_kernel<<<BB * (SS / 128), 512, 147456, stream>>>(q, bq, cvb, ksum, Bimg, out);
}